// Round 1
// 183.071 us; speedup vs baseline: 1.1320x; 1.1320x over previous
//
#include <hip/hip_runtime.h>

typedef unsigned short u16;
typedef unsigned int   u32;
typedef __attribute__((ext_vector_type(8))) short bf16x8;   // 8 bf16 = 4 VGPRs
typedef __attribute__((ext_vector_type(4))) float f32x4;

#define PP 32768          // H*W*T
#define CC 64

__device__ __forceinline__ u16 f2b(float f) {
    u32 u; __builtin_memcpy(&u, &f, 4);
    u32 r = (u + 0x7FFFu + ((u >> 16) & 1u)) >> 16;
    return (u16)r;
}
__device__ __forceinline__ void unpack2(u32 v, float& lo, float& hi) {
    u32 a = v << 16; u32 b = v & 0xFFFF0000u;
    __builtin_memcpy(&lo, &a, 4); __builtin_memcpy(&hi, &b, 4);
}
__device__ __forceinline__ u32 pack2(float lo, float hi) {
    return (u32)f2b(lo) | ((u32)f2b(hi) << 16);
}

// ---------------- K1: style dot, one output channel per block --------------
__global__ __launch_bounds__(64) void k_style2(
        const float* __restrict__ style, const float* __restrict__ qkv_lw,
        const float* __restrict__ qkv_lb, const float* __restrict__ proj_lw,
        const float* __restrict__ proj_lb, float* __restrict__ s_out) {
    int id = blockIdx.x;
    int b = id >> 7, sel = (id >> 6) & 1, o = id & 63;
    int t = threadIdx.x;
    const float* lw = sel ? proj_lw : qkv_lw;
    const float* lb = sel ? proj_lb : qkv_lb;
    const float* st = style + b * 512 + t * 8;
    const float* wr = lw + (size_t)o * 512 + t * 8;
    float4 s0 = *(const float4*)st, s1 = *(const float4*)(st + 4);
    float4 w0 = *(const float4*)wr, w1 = *(const float4*)(wr + 4);
    float p = s0.x*w0.x + s0.y*w0.y + s0.z*w0.z + s0.w*w0.w
            + s1.x*w1.x + s1.y*w1.y + s1.z*w1.z + s1.w*w1.w;
    #pragma unroll
    for (int off = 32; off > 0; off >>= 1) p += __shfl_xor(p, off, 64);
    if (t == 0) s_out[b * 128 + sel * 64 + o] = p + lb[o];
}

// ---------------- K2: normalized modulated weights + S zero ----------------
// wqkT[b][e][o<128] fp32; wv_bf[b][ich][e] bf16 (e-contig for MFMA A-frags);
// wpT[b][i][o] fp32.
__global__ __launch_bounds__(64) void k_wnorm(
        const float* __restrict__ qkv_w, const float* __restrict__ proj_w,
        const float* __restrict__ s, float* __restrict__ wqkT,
        u16* __restrict__ wv_bf, float* __restrict__ wpT, float* __restrict__ S) {
    int id = blockIdx.x;           // 4 * 256
    int b = id >> 8, o = id & 255, i = threadIdx.x;
    if (i < 32) S[(size_t)id * 32 + i] = 0.f;     // 1024*32 = |S| exactly
    float wv;
    if (o < 192) wv = qkv_w[o * 64 + i] * s[b * 128 + i];
    else         wv = proj_w[(o - 192) * 64 + i] * s[b * 128 + 64 + i];
    float sq = wv * wv;
    #pragma unroll
    for (int off = 32; off > 0; off >>= 1) sq += __shfl_xor(sq, off, 64);
    float val = wv * rsqrtf(sq + 1e-8f);
    if (o < 128)      wqkT[((size_t)b * 64 + i) * 128 + o]            = val;
    else if (o < 192) wv_bf[((size_t)b * 64 + (o - 128)) * 64 + i]    = f2b(val);
    else              wpT [((size_t)b * 64 + i) * 64 + (o - 192)]     = val;
}

// ---------------- K3: fused q,k recompute + scores (unchanged) -------------
__global__ __launch_bounds__(256) void k_fscores(
        const float* __restrict__ x, const float* __restrict__ wqkT,
        const float* __restrict__ qnp, const float* __restrict__ qbp,
        const float* __restrict__ qnoise, float* __restrict__ S) {
    int bidx = blockIdx.x;
    int b = bidx >> 8, n = (bidx >> 5) & 7, chunk = bidx & 31;
    int tid = threadIdx.x;
    __shared__ float q_lds[8192];     // [c<8][hw_l*32+t]
    __shared__ float k_lds[8192];
    float qa[8][4], ka[8][4];
    #pragma unroll
    for (int c = 0; c < 8; ++c)
        #pragma unroll
        for (int j = 0; j < 4; ++j) { qa[c][j] = 0.f; ka[c][j] = 0.f; }
    const float* xb = x + (size_t)b * CC * PP + chunk * 1024 + tid * 4;
    const float* wb = wqkT + (size_t)b * 8192 + n * 8;
    #pragma unroll 2
    for (int e = 0; e < 64; ++e) {
        float4 xv = *(const float4*)(xb + (size_t)e * PP);
        float xr[4] = {xv.x, xv.y, xv.z, xv.w};
        const float* wr = wb + e * 128;          // wave-uniform -> s_load
        #pragma unroll
        for (int c = 0; c < 8; ++c) {
            float wq_ = wr[c], wk_ = wr[64 + c];
            #pragma unroll
            for (int j = 0; j < 4; ++j) {
                qa[c][j] = fmaf(wq_, xr[j], qa[c][j]);
                ka[c][j] = fmaf(wk_, xr[j], ka[c][j]);
            }
        }
    }
    {
        float4 nz4 = *(const float4*)(qnoise + (size_t)b * PP + chunk * 1024 + tid * 4);
        float nz[4] = {nz4.x, nz4.y, nz4.z, nz4.w};
        #pragma unroll
        for (int c = 0; c < 8; ++c) {
            float qn = qnp[n * 8 + c], qb_ = qbp[n * 8 + c];
            float kn = qnp[64 + n * 8 + c], kb_ = qbp[64 + n * 8 + c];
            float4 qo, ko;
            qo.x = qa[c][0] + qn * nz[0] + qb_;  ko.x = ka[c][0] + kn * nz[0] + kb_;
            qo.y = qa[c][1] + qn * nz[1] + qb_;  ko.y = ka[c][1] + kn * nz[1] + kb_;
            qo.z = qa[c][2] + qn * nz[2] + qb_;  ko.z = ka[c][2] + kn * nz[2] + kb_;
            qo.w = qa[c][3] + qn * nz[3] + qb_;  ko.w = ka[c][3] + kn * nz[3] + kb_;
            *(float4*)&q_lds[c * 1024 + tid * 4] = qo;
            *(float4*)&k_lds[c * 1024 + tid * 4] = ko;
        }
    }
    __syncthreads();
    int wave = tid >> 6, lane = tid & 63;
    int ig = lane >> 3, jg = lane & 7;
    float acc[16];
    #pragma unroll
    for (int q = 0; q < 16; ++q) acc[q] = 0.f;
    #pragma unroll 4
    for (int i = 0; i < 64; ++i) {
        int e = wave * 64 + i, c = e >> 5, hl = e & 31;
        float4 qv = *(const float4*)&q_lds[c * 1024 + hl * 32 + ig * 4];
        float4 kv = *(const float4*)&k_lds[c * 1024 + hl * 32 + jg * 4];
        float qa4[4] = {qv.x, qv.y, qv.z, qv.w};
        float ka4[4] = {kv.x, kv.y, kv.z, kv.w};
        #pragma unroll
        for (int ii = 0; ii < 4; ++ii)
            #pragma unroll
            for (int jj = 0; jj < 4; ++jj)
                acc[ii * 4 + jj] = fmaf(qa4[ii], ka4[jj], acc[ii * 4 + jj]);
    }
    __syncthreads();                  // q_lds dead -> reduction scratch
    #pragma unroll
    for (int t = 0; t < 16; ++t) q_lds[t * 256 + tid] = acc[t];
    __syncthreads();
    if (wave == 0) {
        float* Sb = S + ((size_t)b * 8 + n) * 1024;
        #pragma unroll
        for (int t = 0; t < 16; ++t) {
            float s2 = q_lds[t * 256 + lane]       + q_lds[t * 256 + 64 + lane]
                     + q_lds[t * 256 + 128 + lane] + q_lds[t * 256 + 192 + lane];
            int ii = t >> 2, jj = t & 3;
            atomicAdd(&Sb[(ig * 4 + ii) * 32 + jg * 4 + jj], s2);
        }
    }
}

// ---------------- K4: softmax + MFMA v + MFMA PV + fp32 proj ---------------
// grid 1024 = b x hwblk4; 256 thr (4 waves); LDS 74.75 KB -> 2 blocks/CU.
// Phase1/2 on v_mfma_f32_16x16x32_bf16; phase 3 unchanged fp32 VALU.
__global__ __launch_bounds__(256) void k_out(
        const float* __restrict__ x, const u16* __restrict__ wv_bf,
        const float* __restrict__ qnp, const float* __restrict__ qbp,
        const float* __restrict__ qnoise, const float* __restrict__ Sg,
        const float* __restrict__ wpT, const float* __restrict__ pnp,
        const float* __restrict__ pbp, const float* __restrict__ pnoise,
        float* __restrict__ out) {
    int bidx = blockIdx.x;
    int b = bidx >> 8, hw0 = (bidx & 255) * 4;
    int tid = threadIdx.x;
    __shared__ u32   P32s[5120];   // 20 KB: [h][i(t)] bf16 pairs, row stride 20 u32 (16B-aligned b128 B-frags)
    __shared__ u16   V16[10240];   // 20 KB: [rv=ich*4+hwl][t] bf16, 80B stride, XOR-swizzled (bits 5-6 ^ (rv>>4)&3)
    __shared__ float uni[8448];    // 33 KB: stage: XT bf16 [pos][e] @70 u16 stride; ph2+: As fp32 [i*132+hwl*33+t]
    // ---- fused softmax -> P bf16 (identical numerics to previous version) ----
    {
        int n = tid >> 5, i2 = tid & 31;
        const float* Srow = Sg + ((size_t)b * 8 + n) * 1024 + i2 * 32;
        float v[32];
        #pragma unroll
        for (int j4 = 0; j4 < 8; ++j4) {
            float4 s4 = *(const float4*)(Srow + j4 * 4);
            v[j4 * 4] = s4.x; v[j4 * 4 + 1] = s4.y;
            v[j4 * 4 + 2] = s4.z; v[j4 * 4 + 3] = s4.w;
        }
        float slope = exp2f(-(float)(n + 1));
        float m = -3e38f;
        #pragma unroll
        for (int j = 0; j < 32; ++j) {
            float val = v[j] * 0.011048543456039806f - slope * fabsf((float)(i2 - j));
            if (j <= i2) val = -1e18f;             // tril incl. diag masked
            v[j] = val; m = fmaxf(m, val);
        }
        float ssum = 0.f;
        #pragma unroll
        for (int j = 0; j < 32; ++j) { float e2 = expf(v[j] - m); v[j] = e2; ssum += e2; }
        float r = 1.f / ssum;
        #pragma unroll
        for (int jp = 0; jp < 16; ++jp)
            P32s[n * 640 + i2 * 20 + jp] = pack2(v[2 * jp] * r, v[2 * jp + 1] * r);
    }
    // ---- stage x -> XT bf16 [pos][e], row stride 70 u16 = 35 dw (35%32=3 -> conflict-free reads) ----
    {
        u16* XTu = (u16*)uni;
        const float4* xb4 = (const float4*)(x + (size_t)b * CC * PP + (size_t)hw0 * 32);
        #pragma unroll
        for (int r4 = 0; r4 < 8; ++r4) {
            int idx = r4 * 256 + tid;             // 0..2047 float4s
            int e = idx >> 5, rem = idx & 31, posq = rem * 4;
            float4 xv = xb4[(size_t)e * (PP / 4) + rem];
            XTu[(posq + 0) * 70 + e] = f2b(xv.x);
            XTu[(posq + 1) * 70 + e] = f2b(xv.y);
            XTu[(posq + 2) * 70 + e] = f2b(xv.z);
            XTu[(posq + 3) * 70 + e] = f2b(xv.w);
        }
    }
    __syncthreads();
    int wv_ = tid >> 6, l = tid & 63, tl = l & 15, g = l >> 4;
    // ---- phase 1 (MFMA): V[ich][pos] = Wv x + noise + bias -> V16 bf16 ----
    // wave w owns hwl=w (n-tiles 2w,2w+1); A = wv_bf[ich][e] (global 16B frags).
    {
        const u32* XT32 = (const u32*)uni;
        const u16* wvb = wv_bf + (size_t)b * 4096;
        bf16x8 Af[4][2];
        #pragma unroll
        for (int mt = 0; mt < 4; ++mt)
            #pragma unroll
            for (int k = 0; k < 2; ++k)
                Af[mt][k] = *(const bf16x8*)(wvb + (mt * 16 + tl) * 64 + k * 32 + g * 8);
        #pragma unroll
        for (int nh = 0; nh < 2; ++nh) {
            int nt = 2 * wv_ + nh;
            f32x4 acc[4];
            #pragma unroll
            for (int mt = 0; mt < 4; ++mt) acc[mt] = (f32x4){0.f, 0.f, 0.f, 0.f};
            #pragma unroll
            for (int k = 0; k < 2; ++k) {
                int pos = nt * 16 + tl;
                union { bf16x8 v8; u32 d[4]; } B;
                const u32* xp = XT32 + pos * 35 + k * 16 + g * 4;
                B.d[0] = xp[0]; B.d[1] = xp[1]; B.d[2] = xp[2]; B.d[3] = xp[3];
                #pragma unroll
                for (int mt = 0; mt < 4; ++mt)
                    acc[mt] = __builtin_amdgcn_mfma_f32_16x16x32_bf16(Af[mt][k], B.v8, acc[mt], 0, 0, 0);
            }
            int t = (nt & 1) * 16 + tl;
            float nz = qnoise[(size_t)b * PP + (size_t)(hw0 + wv_) * 32 + t];
            #pragma unroll
            for (int mt = 0; mt < 4; ++mt) {
                float4 np4 = *(const float4*)(qnp + 128 + mt * 16 + g * 4);
                float4 bp4 = *(const float4*)(qbp + 128 + mt * 16 + g * 4);
                float npr[4] = {np4.x, np4.y, np4.z, np4.w};
                float bpr[4] = {bp4.x, bp4.y, bp4.z, bp4.w};
                #pragma unroll
                for (int j = 0; j < 4; ++j) {
                    int ich = mt * 16 + g * 4 + j;           // D row = (lane>>4)*4 + reg
                    int rv = ich * 4 + wv_;
                    float y = acc[mt][j] + npr[j] * nz + bpr[j];
                    u32 bo = (u32)(rv * 80 + t * 2) ^ ((((u32)rv >> 4) & 3u) << 5);
                    *(u16*)((char*)V16 + bo) = f2b(y);
                }
            }
        }
    }
    __syncthreads();
    // ---- phase 2 (MFMA): A[r][t] = sum_j V[r][j] P[t][j] -> uni fp32 ----
    // wave w owns heads 2w,2w+1; A-frag = V rows (b128 swz), B-frag = P rows (b128).
    {
        #pragma unroll
        for (int hh = 0; hh < 2; ++hh) {
            int h = 2 * wv_ + hh;
            bf16x8 Bp[2];
            #pragma unroll
            for (int n2 = 0; n2 < 2; ++n2) {
                const u32* pp = P32s + h * 640 + (n2 * 16 + tl) * 20 + g * 4;
                union { bf16x8 v8; u32 d[4]; } U;
                U.d[0] = pp[0]; U.d[1] = pp[1]; U.d[2] = pp[2]; U.d[3] = pp[3];
                Bp[n2] = U.v8;
            }
            #pragma unroll
            for (int mt2 = 0; mt2 < 2; ++mt2) {
                int rv = h * 32 + mt2 * 16 + tl;
                u32 bo = ((u32)(rv * 80) + (u32)g * 16) ^ ((((u32)rv >> 4) & 3u) << 5);
                bf16x8 Av = *(const bf16x8*)((const char*)V16 + bo);
                #pragma unroll
                for (int n2 = 0; n2 < 2; ++n2) {
                    f32x4 a4 = (f32x4){0.f, 0.f, 0.f, 0.f};
                    a4 = __builtin_amdgcn_mfma_f32_16x16x32_bf16(Av, Bp[n2], a4, 0, 0, 0);
                    int i = h * 8 + mt2 * 4 + g;             // r = mt2*16+g*4+j -> ich_l = mt2*4+g, hwl = j
                    int t = n2 * 16 + tl;
                    #pragma unroll
                    for (int j = 0; j < 4; ++j)
                        uni[i * 132 + j * 33 + t] = a4[j];
                }
            }
        }
    }
    __syncthreads();
    // ---- phase 3: proj (unchanged fp32 VALU) ----
    {
        int og = tid >> 6, lane = tid & 63;
        int tt = lane & 31, rep = lane >> 5;
        int ogu = __builtin_amdgcn_readfirstlane(og);
        const float* wpt = wpT + (size_t)b * 4096 + ogu * 16;
        float acc[16][2];
        #pragma unroll
        for (int oo = 0; oo < 16; ++oo) { acc[oo][0] = 0.f; acc[oo][1] = 0.f; }
        #pragma unroll 4
        for (int i = 0; i < 64; ++i) {
            float a0 = uni[i * 132 + (rep * 2) * 33 + tt];
            float a1 = uni[i * 132 + (rep * 2) * 33 + 33 + tt];
            const float* wr = wpt + i * 64;   // wave-uniform -> s_load
            #pragma unroll
            for (int oo = 0; oo < 16; ++oo) {
                acc[oo][0] = fmaf(wr[oo], a0, acc[oo][0]);
                acc[oo][1] = fmaf(wr[oo], a1, acc[oo][1]);
            }
        }
        float nz0 = pnoise[(size_t)b * PP + (size_t)(hw0 + rep * 2) * 32 + tt];
        float nz1 = pnoise[(size_t)b * PP + (size_t)(hw0 + rep * 2 + 1) * 32 + tt];
        #pragma unroll
        for (int oo = 0; oo < 16; ++oo) {
            int o = ogu * 16 + oo;
            float npv = pnp[o], bpv = pbp[o];
            size_t base = (size_t)(b * 64 + o) * PP + tt;
            out[base + (size_t)(hw0 + rep * 2) * 32]     = acc[oo][0] + npv * nz0 + bpv;
            out[base + (size_t)(hw0 + rep * 2 + 1) * 32] = acc[oo][1] + npv * nz1 + bpv;
        }
    }
}

// ---------------- sentinels ------------------------------------------------
__global__ __launch_bounds__(256) void k_zero(float* __restrict__ out, int n) {
    int i = blockIdx.x * 256 + threadIdx.x;
    if (i < n) out[i] = 0.f;
}
__global__ void k_code(float* __restrict__ out, float code) { out[0] = code; }

extern "C" void kernel_launch(void* const* d_in, const int* in_sizes, int n_in,
                              void* d_out, int out_size, void* d_ws, size_t ws_size,
                              hipStream_t stream) {
    float* out = (float*)d_out;
    const int exp_sizes[14] = {4*64*32768, 4*512, 192*64, 64*512, 64, 192, 192,
                               4*32768, 64*64, 64*512, 64, 64, 64, 4*32768};
    bool ok = (n_in == 14) && (out_size == 4*64*32768);
    if (ok) for (int k = 0; k < 14; ++k) ok = ok && (in_sizes[k] == exp_sizes[k]);
    if (!ok) {
        k_zero<<<(out_size + 255) / 256, 256, 0, stream>>>(out, out_size);
        k_code<<<1, 1, 0, stream>>>(out, 1000.f);
        return;
    }
    if (ws_size < 395264) {
        k_zero<<<(out_size + 255) / 256, 256, 0, stream>>>(out, out_size);
        k_code<<<1, 1, 0, stream>>>(out, 2000.f + (float)(ws_size >> 20));
        return;
    }
    char* ws = (char*)d_ws;
    float* S     = (float*)ws;               // 128 KB (4,8,32,32)
    float* wqkT  = (float*)(ws + 131072);    // 128 KB (4,64e,128o)
    u16*   wv_bf = (u16*)  (ws + 262144);    //  32 KB used of 64 KB (4,64ich,64e) bf16
    float* wpT   = (float*)(ws + 327680);    //  64 KB (4,64i,64o)
    float* s_sty = (float*)(ws + 393216);    //   2 KB (4,128)

    k_style2 <<<512,  64,  0, stream>>>((const float*)d_in[1], (const float*)d_in[3],
                                        (const float*)d_in[4], (const float*)d_in[9],
                                        (const float*)d_in[10], s_sty);
    k_wnorm  <<<1024, 64,  0, stream>>>((const float*)d_in[2], (const float*)d_in[8],
                                        s_sty, wqkT, wv_bf, wpT, S);
    k_fscores<<<1024, 256, 0, stream>>>((const float*)d_in[0], wqkT,
                                        (const float*)d_in[5], (const float*)d_in[6],
                                        (const float*)d_in[7], S);
    k_out    <<<1024, 256, 0, stream>>>((const float*)d_in[0], wv_bf,
                                        (const float*)d_in[5], (const float*)d_in[6],
                                        (const float*)d_in[7], S, wpT,
                                        (const float*)d_in[11], (const float*)d_in[12],
                                        (const float*)d_in[13], out);
    hipError_t e = hipGetLastError();
    if (e != hipSuccess) {
        k_zero<<<(out_size + 255) / 256, 256, 0, stream>>>(out, out_size);
        k_code<<<1, 1, 0, stream>>>(out, 3000.f + (float)e);
    }
}

// Round 2
// 173.761 us; speedup vs baseline: 1.1926x; 1.0536x over previous
//
#include <hip/hip_runtime.h>

typedef unsigned short u16;
typedef unsigned int   u32;
typedef __attribute__((ext_vector_type(8))) short bf16x8;   // 8 bf16 = 4 VGPRs
typedef __attribute__((ext_vector_type(4))) float f32x4;

#define PP 32768          // H*W*T
#define CC 64

__device__ __forceinline__ u16 f2b(float f) {
    u32 u; __builtin_memcpy(&u, &f, 4);
    u32 r = (u + 0x7FFFu + ((u >> 16) & 1u)) >> 16;
    return (u16)r;
}
__device__ __forceinline__ void unpack2(u32 v, float& lo, float& hi) {
    u32 a = v << 16; u32 b = v & 0xFFFF0000u;
    __builtin_memcpy(&lo, &a, 4); __builtin_memcpy(&hi, &b, 4);
}
__device__ __forceinline__ u32 pack2(float lo, float hi) {
    return (u32)f2b(lo) | ((u32)f2b(hi) << 16);
}

// ---------------- K1: style dot, one output channel per block --------------
__global__ __launch_bounds__(64) void k_style2(
        const float* __restrict__ style, const float* __restrict__ qkv_lw,
        const float* __restrict__ qkv_lb, const float* __restrict__ proj_lw,
        const float* __restrict__ proj_lb, float* __restrict__ s_out) {
    int id = blockIdx.x;
    int b = id >> 7, sel = (id >> 6) & 1, o = id & 63;
    int t = threadIdx.x;
    const float* lw = sel ? proj_lw : qkv_lw;
    const float* lb = sel ? proj_lb : qkv_lb;
    const float* st = style + b * 512 + t * 8;
    const float* wr = lw + (size_t)o * 512 + t * 8;
    float4 s0 = *(const float4*)st, s1 = *(const float4*)(st + 4);
    float4 w0 = *(const float4*)wr, w1 = *(const float4*)(wr + 4);
    float p = s0.x*w0.x + s0.y*w0.y + s0.z*w0.z + s0.w*w0.w
            + s1.x*w1.x + s1.y*w1.y + s1.z*w1.z + s1.w*w1.w;
    #pragma unroll
    for (int off = 32; off > 0; off >>= 1) p += __shfl_xor(p, off, 64);
    if (t == 0) s_out[b * 128 + sel * 64 + o] = p + lb[o];
}

// ---------------- K2: normalized modulated weights + S zero ----------------
// wqk_bf[b]: 256 rows x 64e u16: rows 0..127 = hi(q0-63,k0-63), rows 128..255 = lo.
// wv_bf[b][ich][e] bf16; wpT[b][i][o] fp32.
__global__ __launch_bounds__(64) void k_wnorm(
        const float* __restrict__ qkv_w, const float* __restrict__ proj_w,
        const float* __restrict__ s, u16* __restrict__ wqk_bf,
        u16* __restrict__ wv_bf, float* __restrict__ wpT, float* __restrict__ S) {
    int id = blockIdx.x;           // 4 * 256
    int b = id >> 8, o = id & 255, i = threadIdx.x;
    if (i < 32) S[(size_t)id * 32 + i] = 0.f;     // 1024*32 = |S| exactly
    float wv;
    if (o < 192) wv = qkv_w[o * 64 + i] * s[b * 128 + i];
    else         wv = proj_w[(o - 192) * 64 + i] * s[b * 128 + 64 + i];
    float sq = wv * wv;
    #pragma unroll
    for (int off = 32; off > 0; off >>= 1) sq += __shfl_xor(sq, off, 64);
    float val = wv * rsqrtf(sq + 1e-8f);
    if (o < 128) {
        // hi = truncated bf16, lo = truncated bf16 of exact residual
        u32 uv = __float_as_uint(val);
        float res = val - __uint_as_float(uv & 0xFFFF0000u);
        wqk_bf[((size_t)b * 256 + o) * 64 + i]       = (u16)(uv >> 16);
        wqk_bf[((size_t)b * 256 + 128 + o) * 64 + i] = (u16)(__float_as_uint(res) >> 16);
    }
    else if (o < 192) wv_bf[((size_t)b * 64 + (o - 128)) * 64 + i] = f2b(val);
    else              wpT [((size_t)b * 64 + i) * 64 + (o - 192)]  = val;
}

// ---------------- K3: MFMA q,k recompute + MFMA scores ---------------------
// grid 1024 = b x n(8) x chunk(32 hw); 256 thr (4 waves); LDS ~45.6 KB -> 3 blk/CU.
// 8 sub-chunks of 128 pos. All operands hi/lo split -> S is fp32-grade.
__global__ __launch_bounds__(256) void k_fscores(
        const float* __restrict__ x, const u16* __restrict__ wqk_bf,
        const float* __restrict__ qnp, const float* __restrict__ qbp,
        const float* __restrict__ qnoise, float* __restrict__ S) {
    int bidx = blockIdx.x;
    int b = bidx >> 8, n = (bidx >> 5) & 7, chunk = bidx & 31;
    int tid = threadIdx.x;
    __shared__ u32   XTh[4480];    // [pos 128][e2 35] hi pairs (u16 stride 70)
    __shared__ u32   XTl[4480];    // lo pairs
    __shared__ float NZ[128];
    __shared__ u16   QTh[1288], QTl[1288], KTh[1288], KTl[1288]; // [t 32][r stride 40]

    int wv = tid >> 6, l = tid & 63, tl = l & 15, g = l >> 4;
    // A-frag weight rows: tl<8 -> q-ch n*8+tl ; tl>=8 -> k-ch (row 64+n*8+tl-8)
    int wrow = n * 8 + (tl & 7) + (tl >> 3) * 64;
    const u16* wpb = wqk_bf + (size_t)b * 16384 + wrow * 64;
    bf16x8 WH0 = *(const bf16x8*)(wpb + g * 8);
    bf16x8 WH1 = *(const bf16x8*)(wpb + 32 + g * 8);
    bf16x8 WL0 = *(const bf16x8*)(wpb + 8192 + g * 8);
    bf16x8 WL1 = *(const bf16x8*)(wpb + 8192 + 32 + g * 8);
    // epilogue params for D rows r = g*4+j : side=(g>>1), c=(g&1)*4+j
    int pidx = (g >> 1) * 64 + n * 8 + (g & 1) * 4;
    float4 np4v = *(const float4*)(qnp + pidx);
    float4 bp4v = *(const float4*)(qbp + pidx);
    int ti = wv >> 1, tj = wv & 1;
    f32x4 sacc = {0.f, 0.f, 0.f, 0.f};

    #pragma unroll 1
    for (int sub = 0; sub < 8; ++sub) {
        // ---- stage x sub-chunk (128 pos x 64 e) as hi/lo bf16, e-paired ----
        const float* xc = x + (size_t)b * CC * PP + chunk * 1024 + sub * 128;
        #pragma unroll
        for (int r2 = 0; r2 < 4; ++r2) {
            int idx = r2 * 256 + tid;            // 0..1023
            int e2 = idx >> 5, rem = idx & 31;   // e-pair, float4-within-row
            const float* pa = xc + (size_t)(2 * e2) * PP + rem * 4;
            float4 fa = *(const float4*)pa;
            float4 fb = *(const float4*)(pa + PP);
            #pragma unroll
            for (int j = 0; j < 4; ++j) {
                float va = (&fa.x)[j], vb = (&fb.x)[j];
                u32 ua = __float_as_uint(va), ub = __float_as_uint(vb);
                float ra = va - __uint_as_float(ua & 0xFFFF0000u);
                float rb = vb - __uint_as_float(ub & 0xFFFF0000u);
                int p = (rem * 4 + j) * 35 + e2;
                XTh[p] = (ua >> 16) | (ub & 0xFFFF0000u);
                XTl[p] = (__float_as_uint(ra) >> 16) | (__float_as_uint(rb) & 0xFFFF0000u);
            }
        }
        if (tid < 32)
            *(float4*)&NZ[tid * 4] = *(const float4*)
                (qnoise + (size_t)b * PP + chunk * 1024 + sub * 128 + tid * 4);
        __syncthreads();
        // ---- phase 1: q||k = W x  (M=16, 8 Ntiles; wave owns nt=2wv,2wv+1) ----
        #pragma unroll
        for (int nh = 0; nh < 2; ++nh) {
            int nt = wv * 2 + nh, pos = nt * 16 + tl;
            f32x4 a = {0.f, 0.f, 0.f, 0.f};
            #pragma unroll
            for (int k = 0; k < 2; ++k) {
                union { bf16x8 v; u32 d[4]; } BH, BL;
                const u32* ph = &XTh[pos * 35 + k * 16 + g * 4];
                const u32* pl = &XTl[pos * 35 + k * 16 + g * 4];
                BH.d[0] = ph[0]; BH.d[1] = ph[1]; BH.d[2] = ph[2]; BH.d[3] = ph[3];
                BL.d[0] = pl[0]; BL.d[1] = pl[1]; BL.d[2] = pl[2]; BL.d[3] = pl[3];
                bf16x8 WHk = k ? WH1 : WH0;
                bf16x8 WLk = k ? WL1 : WL0;
                a = __builtin_amdgcn_mfma_f32_16x16x32_bf16(WHk, BH.v, a, 0, 0, 0);
                a = __builtin_amdgcn_mfma_f32_16x16x32_bf16(WHk, BL.v, a, 0, 0, 0);
                a = __builtin_amdgcn_mfma_f32_16x16x32_bf16(WLk, BH.v, a, 0, 0, 0);
            }
            // epilogue: +noise/bias, hi/lo split, transpose-write [t][r=hwl*8+c]
            float nz = NZ[pos];
            int t = pos & 31, hwl = pos >> 5, side = g >> 1, g1 = g & 1;
            u32 uu[4], lu[4];
            #pragma unroll
            for (int j = 0; j < 4; ++j) {
                float yv = a[j] + (&np4v.x)[j] * nz + (&bp4v.x)[j];
                u32 uy = __float_as_uint(yv);
                float res = yv - __uint_as_float(uy & 0xFFFF0000u);
                uu[j] = uy; lu[j] = __float_as_uint(res);
            }
            int off = t * 40 + hwl * 8 + g1 * 4;
            u16* dh = (side ? KTh : QTh) + off;
            u16* dl = (side ? KTl : QTl) + off;
            *(uint2*)dh = make_uint2((uu[0] >> 16) | (uu[1] & 0xFFFF0000u),
                                     (uu[2] >> 16) | (uu[3] & 0xFFFF0000u));
            *(uint2*)dl = make_uint2((lu[0] >> 16) | (lu[1] & 0xFFFF0000u),
                                     (lu[2] >> 16) | (lu[3] & 0xFFFF0000u));
        }
        __syncthreads();
        // ---- score: wave tile (ti,tj); K=32 over r=(hwl,c); acc across subs ----
        {
            int ar = (ti * 16 + tl) * 40 + g * 8;
            int br = (tj * 16 + tl) * 40 + g * 8;
            bf16x8 Ah = *(const bf16x8*)&QTh[ar];
            bf16x8 Al = *(const bf16x8*)&QTl[ar];
            bf16x8 Bh = *(const bf16x8*)&KTh[br];
            bf16x8 Bl = *(const bf16x8*)&KTl[br];
            sacc = __builtin_amdgcn_mfma_f32_16x16x32_bf16(Ah, Bh, sacc, 0, 0, 0);
            sacc = __builtin_amdgcn_mfma_f32_16x16x32_bf16(Ah, Bl, sacc, 0, 0, 0);
            sacc = __builtin_amdgcn_mfma_f32_16x16x32_bf16(Al, Bh, sacc, 0, 0, 0);
        }
    }
    float* Sb = S + ((size_t)b * 8 + n) * 1024;
    #pragma unroll
    for (int jj = 0; jj < 4; ++jj)
        atomicAdd(&Sb[(ti * 16 + g * 4 + jj) * 32 + tj * 16 + tl], sacc[jj]);
}

// ---------------- K4: softmax + MFMA v + MFMA PV + fp32 proj ---------------
// grid 1024 = b x hwblk4; 256 thr (4 waves); LDS 74.75 KB -> 2 blocks/CU.
__global__ __launch_bounds__(256) void k_out(
        const float* __restrict__ x, const u16* __restrict__ wv_bf,
        const float* __restrict__ qnp, const float* __restrict__ qbp,
        const float* __restrict__ qnoise, const float* __restrict__ Sg,
        const float* __restrict__ wpT, const float* __restrict__ pnp,
        const float* __restrict__ pbp, const float* __restrict__ pnoise,
        float* __restrict__ out) {
    int bidx = blockIdx.x;
    int b = bidx >> 8, hw0 = (bidx & 255) * 4;
    int tid = threadIdx.x;
    __shared__ u32   P32s[5120];   // 20 KB: [h][i(t)] bf16 pairs, row stride 20 u32
    __shared__ u16   V16[10240];   // 20 KB: [rv=ich*4+hwl][t] bf16, 80B stride, XOR swz
    __shared__ float uni[8448];    // 33 KB: stage XT bf16 [pos][e]@70; ph2+: As fp32
    // ---- fused softmax -> P bf16 ----
    {
        int n = tid >> 5, i2 = tid & 31;
        const float* Srow = Sg + ((size_t)b * 8 + n) * 1024 + i2 * 32;
        float v[32];
        #pragma unroll
        for (int j4 = 0; j4 < 8; ++j4) {
            float4 s4 = *(const float4*)(Srow + j4 * 4);
            v[j4 * 4] = s4.x; v[j4 * 4 + 1] = s4.y;
            v[j4 * 4 + 2] = s4.z; v[j4 * 4 + 3] = s4.w;
        }
        float slope = exp2f(-(float)(n + 1));
        float m = -3e38f;
        #pragma unroll
        for (int j = 0; j < 32; ++j) {
            float val = v[j] * 0.011048543456039806f - slope * fabsf((float)(i2 - j));
            if (j <= i2) val = -1e18f;             // tril incl. diag masked
            v[j] = val; m = fmaxf(m, val);
        }
        float ssum = 0.f;
        #pragma unroll
        for (int j = 0; j < 32; ++j) { float e2 = expf(v[j] - m); v[j] = e2; ssum += e2; }
        float r = 1.f / ssum;
        #pragma unroll
        for (int jp = 0; jp < 16; ++jp)
            P32s[n * 640 + i2 * 20 + jp] = pack2(v[2 * jp] * r, v[2 * jp + 1] * r);
    }
    // ---- stage x -> XT bf16 [pos][e], row stride 70 u16 ----
    {
        u16* XTu = (u16*)uni;
        const float4* xb4 = (const float4*)(x + (size_t)b * CC * PP + (size_t)hw0 * 32);
        #pragma unroll
        for (int r4 = 0; r4 < 8; ++r4) {
            int idx = r4 * 256 + tid;             // 0..2047 float4s
            int e = idx >> 5, rem = idx & 31, posq = rem * 4;
            float4 xv = xb4[(size_t)e * (PP / 4) + rem];
            XTu[(posq + 0) * 70 + e] = f2b(xv.x);
            XTu[(posq + 1) * 70 + e] = f2b(xv.y);
            XTu[(posq + 2) * 70 + e] = f2b(xv.z);
            XTu[(posq + 3) * 70 + e] = f2b(xv.w);
        }
    }
    __syncthreads();
    int wv_ = tid >> 6, l = tid & 63, tl = l & 15, g = l >> 4;
    // ---- phase 1 (MFMA): V = Wv x + noise + bias -> V16 bf16 ----
    {
        const u32* XT32 = (const u32*)uni;
        const u16* wvb = wv_bf + (size_t)b * 4096;
        bf16x8 Af[4][2];
        #pragma unroll
        for (int mt = 0; mt < 4; ++mt)
            #pragma unroll
            for (int k = 0; k < 2; ++k)
                Af[mt][k] = *(const bf16x8*)(wvb + (mt * 16 + tl) * 64 + k * 32 + g * 8);
        #pragma unroll
        for (int nh = 0; nh < 2; ++nh) {
            int nt = 2 * wv_ + nh;
            f32x4 acc[4];
            #pragma unroll
            for (int mt = 0; mt < 4; ++mt) acc[mt] = (f32x4){0.f, 0.f, 0.f, 0.f};
            #pragma unroll
            for (int k = 0; k < 2; ++k) {
                int pos = nt * 16 + tl;
                union { bf16x8 v8; u32 d[4]; } B;
                const u32* xp = XT32 + pos * 35 + k * 16 + g * 4;
                B.d[0] = xp[0]; B.d[1] = xp[1]; B.d[2] = xp[2]; B.d[3] = xp[3];
                #pragma unroll
                for (int mt = 0; mt < 4; ++mt)
                    acc[mt] = __builtin_amdgcn_mfma_f32_16x16x32_bf16(Af[mt][k], B.v8, acc[mt], 0, 0, 0);
            }
            int t = (nt & 1) * 16 + tl;
            float nz = qnoise[(size_t)b * PP + (size_t)(hw0 + wv_) * 32 + t];
            #pragma unroll
            for (int mt = 0; mt < 4; ++mt) {
                float4 np4 = *(const float4*)(qnp + 128 + mt * 16 + g * 4);
                float4 bp4 = *(const float4*)(qbp + 128 + mt * 16 + g * 4);
                float npr[4] = {np4.x, np4.y, np4.z, np4.w};
                float bpr[4] = {bp4.x, bp4.y, bp4.z, bp4.w};
                #pragma unroll
                for (int j = 0; j < 4; ++j) {
                    int ich = mt * 16 + g * 4 + j;
                    int rv = ich * 4 + wv_;
                    float y = acc[mt][j] + npr[j] * nz + bpr[j];
                    u32 bo = (u32)(rv * 80 + t * 2) ^ ((((u32)rv >> 4) & 3u) << 5);
                    *(u16*)((char*)V16 + bo) = f2b(y);
                }
            }
        }
    }
    __syncthreads();
    // ---- phase 2 (MFMA): A[r][t] = sum_j V[r][j] P[t][j] -> uni fp32 ----
    {
        #pragma unroll
        for (int hh = 0; hh < 2; ++hh) {
            int h = 2 * wv_ + hh;
            bf16x8 Bp[2];
            #pragma unroll
            for (int n2 = 0; n2 < 2; ++n2) {
                const u32* pp = P32s + h * 640 + (n2 * 16 + tl) * 20 + g * 4;
                union { bf16x8 v8; u32 d[4]; } U;
                U.d[0] = pp[0]; U.d[1] = pp[1]; U.d[2] = pp[2]; U.d[3] = pp[3];
                Bp[n2] = U.v8;
            }
            #pragma unroll
            for (int mt2 = 0; mt2 < 2; ++mt2) {
                int rv = h * 32 + mt2 * 16 + tl;
                u32 bo = ((u32)(rv * 80) + (u32)g * 16) ^ ((((u32)rv >> 4) & 3u) << 5);
                bf16x8 Av = *(const bf16x8*)((const char*)V16 + bo);
                #pragma unroll
                for (int n2 = 0; n2 < 2; ++n2) {
                    f32x4 a4 = (f32x4){0.f, 0.f, 0.f, 0.f};
                    a4 = __builtin_amdgcn_mfma_f32_16x16x32_bf16(Av, Bp[n2], a4, 0, 0, 0);
                    int i = h * 8 + mt2 * 4 + g;
                    int t = n2 * 16 + tl;
                    #pragma unroll
                    for (int j = 0; j < 4; ++j)
                        uni[i * 132 + j * 33 + t] = a4[j];
                }
            }
        }
    }
    __syncthreads();
    // ---- phase 3: proj (fp32 VALU) ----
    {
        int og = tid >> 6, lane = tid & 63;
        int tt = lane & 31, rep = lane >> 5;
        int ogu = __builtin_amdgcn_readfirstlane(og);
        const float* wpt = wpT + (size_t)b * 4096 + ogu * 16;
        float acc[16][2];
        #pragma unroll
        for (int oo = 0; oo < 16; ++oo) { acc[oo][0] = 0.f; acc[oo][1] = 0.f; }
        #pragma unroll 4
        for (int i = 0; i < 64; ++i) {
            float a0 = uni[i * 132 + (rep * 2) * 33 + tt];
            float a1 = uni[i * 132 + (rep * 2) * 33 + 33 + tt];
            const float* wr = wpt + i * 64;   // wave-uniform -> s_load
            #pragma unroll
            for (int oo = 0; oo < 16; ++oo) {
                acc[oo][0] = fmaf(wr[oo], a0, acc[oo][0]);
                acc[oo][1] = fmaf(wr[oo], a1, acc[oo][1]);
            }
        }
        float nz0 = pnoise[(size_t)b * PP + (size_t)(hw0 + rep * 2) * 32 + tt];
        float nz1 = pnoise[(size_t)b * PP + (size_t)(hw0 + rep * 2 + 1) * 32 + tt];
        #pragma unroll
        for (int oo = 0; oo < 16; ++oo) {
            int o = ogu * 16 + oo;
            float npv = pnp[o], bpv = pbp[o];
            size_t base = (size_t)(b * 64 + o) * PP + tt;
            out[base + (size_t)(hw0 + rep * 2) * 32]     = acc[oo][0] + npv * nz0 + bpv;
            out[base + (size_t)(hw0 + rep * 2 + 1) * 32] = acc[oo][1] + npv * nz1 + bpv;
        }
    }
}

// ---------------- sentinels ------------------------------------------------
__global__ __launch_bounds__(256) void k_zero(float* __restrict__ out, int n) {
    int i = blockIdx.x * 256 + threadIdx.x;
    if (i < n) out[i] = 0.f;
}
__global__ void k_code(float* __restrict__ out, float code) { out[0] = code; }

extern "C" void kernel_launch(void* const* d_in, const int* in_sizes, int n_in,
                              void* d_out, int out_size, void* d_ws, size_t ws_size,
                              hipStream_t stream) {
    float* out = (float*)d_out;
    const int exp_sizes[14] = {4*64*32768, 4*512, 192*64, 64*512, 64, 192, 192,
                               4*32768, 64*64, 64*512, 64, 64, 64, 4*32768};
    bool ok = (n_in == 14) && (out_size == 4*64*32768);
    if (ok) for (int k = 0; k < 14; ++k) ok = ok && (in_sizes[k] == exp_sizes[k]);
    if (!ok) {
        k_zero<<<(out_size + 255) / 256, 256, 0, stream>>>(out, out_size);
        k_code<<<1, 1, 0, stream>>>(out, 1000.f);
        return;
    }
    if (ws_size < 395264) {
        k_zero<<<(out_size + 255) / 256, 256, 0, stream>>>(out, out_size);
        k_code<<<1, 1, 0, stream>>>(out, 2000.f + (float)(ws_size >> 20));
        return;
    }
    char* ws = (char*)d_ws;
    float* S      = (float*)ws;               // 128 KB (4,8,32,32)
    u16*   wqk_bf = (u16*)  (ws + 131072);    // 128 KB (4, 256 rows hi+lo, 64e) bf16
    u16*   wv_bf  = (u16*)  (ws + 262144);    //  32 KB used (4,64ich,64e) bf16
    float* wpT    = (float*)(ws + 327680);    //  64 KB (4,64i,64o)
    float* s_sty  = (float*)(ws + 393216);    //   2 KB (4,128)

    k_style2 <<<512,  64,  0, stream>>>((const float*)d_in[1], (const float*)d_in[3],
                                        (const float*)d_in[4], (const float*)d_in[9],
                                        (const float*)d_in[10], s_sty);
    k_wnorm  <<<1024, 64,  0, stream>>>((const float*)d_in[2], (const float*)d_in[8],
                                        s_sty, wqk_bf, wv_bf, wpT, S);
    k_fscores<<<1024, 256, 0, stream>>>((const float*)d_in[0], wqk_bf,
                                        (const float*)d_in[5], (const float*)d_in[6],
                                        (const float*)d_in[7], S);
    k_out    <<<1024, 256, 0, stream>>>((const float*)d_in[0], wv_bf,
                                        (const float*)d_in[5], (const float*)d_in[6],
                                        (const float*)d_in[7], S, wpT,
                                        (const float*)d_in[11], (const float*)d_in[12],
                                        (const float*)d_in[13], out);
    hipError_t e = hipGetLastError();
    if (e != hipSuccess) {
        k_zero<<<(out_size + 255) / 256, 256, 0, stream>>>(out, out_size);
        k_code<<<1, 1, 0, stream>>>(out, 3000.f + (float)e);
    }
}

// Round 3
// 165.180 us; speedup vs baseline: 1.2546x; 1.0519x over previous
//
#include <hip/hip_runtime.h>

typedef unsigned short u16;
typedef unsigned int   u32;
typedef __attribute__((ext_vector_type(8))) short bf16x8;   // 8 bf16 = 4 VGPRs
typedef __attribute__((ext_vector_type(4))) float f32x4;

#define PP 32768          // H*W*T
#define CC 64

__device__ __forceinline__ u16 f2b(float f) {
    u32 u; __builtin_memcpy(&u, &f, 4);
    u32 r = (u + 0x7FFFu + ((u >> 16) & 1u)) >> 16;
    return (u16)r;
}
__device__ __forceinline__ u32 pack2(float lo, float hi) {
    return (u32)f2b(lo) | ((u32)f2b(hi) << 16);
}

// ---------------- K1: style dot, one output channel per block --------------
__global__ __launch_bounds__(64) void k_style2(
        const float* __restrict__ style, const float* __restrict__ qkv_lw,
        const float* __restrict__ qkv_lb, const float* __restrict__ proj_lw,
        const float* __restrict__ proj_lb, float* __restrict__ s_out) {
    int id = blockIdx.x;
    int b = id >> 7, sel = (id >> 6) & 1, o = id & 63;
    int t = threadIdx.x;
    const float* lw = sel ? proj_lw : qkv_lw;
    const float* lb = sel ? proj_lb : qkv_lb;
    const float* st = style + b * 512 + t * 8;
    const float* wr = lw + (size_t)o * 512 + t * 8;
    float4 s0 = *(const float4*)st, s1 = *(const float4*)(st + 4);
    float4 w0 = *(const float4*)wr, w1 = *(const float4*)(wr + 4);
    float p = s0.x*w0.x + s0.y*w0.y + s0.z*w0.z + s0.w*w0.w
            + s1.x*w1.x + s1.y*w1.y + s1.z*w1.z + s1.w*w1.w;
    #pragma unroll
    for (int off = 32; off > 0; off >>= 1) p += __shfl_xor(p, off, 64);
    if (t == 0) s_out[b * 128 + sel * 64 + o] = p + lb[o];
}

// ---------------- K2: normalized modulated weights + S zero ----------------
// wqk_bf[b]: 256 rows x 64e u16: rows 0..127 = hi(q0-63,k0-63), rows 128..255 = lo.
// wv_bf[b][ich][e] bf16; wp_bf: hi [b][o][i] u16 + lo at +16384.
__global__ __launch_bounds__(64) void k_wnorm(
        const float* __restrict__ qkv_w, const float* __restrict__ proj_w,
        const float* __restrict__ s, u16* __restrict__ wqk_bf,
        u16* __restrict__ wv_bf, u16* __restrict__ wp_bf, float* __restrict__ S) {
    int id = blockIdx.x;           // 4 * 256
    int b = id >> 8, o = id & 255, i = threadIdx.x;
    if (i < 32) S[(size_t)id * 32 + i] = 0.f;     // 1024*32 = |S| exactly
    float wv;
    if (o < 192) wv = qkv_w[o * 64 + i] * s[b * 128 + i];
    else         wv = proj_w[(o - 192) * 64 + i] * s[b * 128 + 64 + i];
    float sq = wv * wv;
    #pragma unroll
    for (int off = 32; off > 0; off >>= 1) sq += __shfl_xor(sq, off, 64);
    float val = wv * rsqrtf(sq + 1e-8f);
    if (o < 128) {
        u32 uv = __float_as_uint(val);
        float res = val - __uint_as_float(uv & 0xFFFF0000u);
        wqk_bf[((size_t)b * 256 + o) * 64 + i]       = (u16)(uv >> 16);
        wqk_bf[((size_t)b * 256 + 128 + o) * 64 + i] = (u16)(__float_as_uint(res) >> 16);
    }
    else if (o < 192) wv_bf[((size_t)b * 64 + (o - 128)) * 64 + i] = f2b(val);
    else {
        int o2 = o - 192;
        u32 uv = __float_as_uint(val);
        float res = val - __uint_as_float(uv & 0xFFFF0000u);
        wp_bf[((size_t)b * 64 + o2) * 64 + i]         = (u16)(uv >> 16);
        wp_bf[16384 + ((size_t)b * 64 + o2) * 64 + i] = (u16)(__float_as_uint(res) >> 16);
    }
}

// ---------------- K3: MFMA q,k recompute + MFMA scores, 4 heads/block ------
// grid 512 = b(4) x hg(2) x chunk(64 of 16hw); 256 thr; LDS 77.6 KB -> 2 blk/CU.
// 4 sub-chunks of 128 pos; staging amortized over 4 heads (was 1).
__global__ __launch_bounds__(256) void k_fscores(
        const float* __restrict__ x, const u16* __restrict__ wqk_bf,
        const float* __restrict__ qnp, const float* __restrict__ qbp,
        const float* __restrict__ qnoise, float* __restrict__ S) {
    int bidx = blockIdx.x;
    int b = bidx >> 7, hg = (bidx >> 6) & 1, chunk = bidx & 63;
    int tid = threadIdx.x;
    __shared__ u32   XTh[4480];    // [pos 128][e2 35] hi pairs (u16 stride 70)
    __shared__ u32   XTl[4480];    // lo pairs
    __shared__ float NZ[128];
    __shared__ __align__(16) u16 QTh[4][1288], QTl[4][1288];  // [head][t*40 + r]
    __shared__ __align__(16) u16 KTh[4][1288], KTl[4][1288];

    int wv = tid >> 6, l = tid & 63, tl = l & 15, g = l >> 4;
    // A-frag weights for 4 heads: tl<8 -> q-ch, tl>=8 -> k-ch (row +64)
    bf16x8 WH[4][2], WL[4][2];
    #pragma unroll
    for (int mt = 0; mt < 4; ++mt) {
        int n = hg * 4 + mt;
        int wrow = n * 8 + (tl & 7) + (tl >> 3) * 64;
        const u16* wpb = wqk_bf + (size_t)b * 16384 + wrow * 64;
        #pragma unroll
        for (int k = 0; k < 2; ++k) {
            WH[mt][k] = *(const bf16x8*)(wpb + k * 32 + g * 8);
            WL[mt][k] = *(const bf16x8*)(wpb + 8192 + k * 32 + g * 8);
        }
    }
    // epilogue params per head: D rows r=g*4+j -> side=(g>>1), c=(g&1)*4+j
    float4 np4[4], bp4[4];
    #pragma unroll
    for (int mt = 0; mt < 4; ++mt) {
        int pidx = (g >> 1) * 64 + (hg * 4 + mt) * 8 + (g & 1) * 4;
        np4[mt] = *(const float4*)(qnp + pidx);
        bp4[mt] = *(const float4*)(qbp + pidx);
    }
    int ti = wv >> 1, tj = wv & 1;
    f32x4 sacc[4];
    #pragma unroll
    for (int h = 0; h < 4; ++h) sacc[h] = (f32x4){0.f, 0.f, 0.f, 0.f};

    #pragma unroll 1
    for (int sub = 0; sub < 4; ++sub) {
        // ---- stage x sub-chunk (128 pos x 64 e) as hi/lo bf16, e-paired ----
        const float* xc = x + (size_t)b * CC * PP + chunk * 512 + sub * 128;
        #pragma unroll
        for (int r2 = 0; r2 < 4; ++r2) {
            int idx = r2 * 256 + tid;            // 0..1023
            int e2 = idx >> 5, rem = idx & 31;   // e-pair, float4-within-row
            const float* pa = xc + (size_t)(2 * e2) * PP + rem * 4;
            float4 fa = *(const float4*)pa;
            float4 fb = *(const float4*)(pa + PP);
            #pragma unroll
            for (int j = 0; j < 4; ++j) {
                float va = (&fa.x)[j], vb = (&fb.x)[j];
                u32 ua = __float_as_uint(va), ub = __float_as_uint(vb);
                float ra = va - __uint_as_float(ua & 0xFFFF0000u);
                float rb = vb - __uint_as_float(ub & 0xFFFF0000u);
                int p = (rem * 4 + j) * 35 + e2;
                XTh[p] = (ua >> 16) | (ub & 0xFFFF0000u);
                XTl[p] = (__float_as_uint(ra) >> 16) | (__float_as_uint(rb) & 0xFFFF0000u);
            }
        }
        if (tid < 32)
            *(float4*)&NZ[tid * 4] = *(const float4*)
                (qnoise + (size_t)b * PP + chunk * 512 + sub * 128 + tid * 4);
        __syncthreads();
        // ---- phase 1: q||k for 4 heads; wave owns ntiles 2wv,2wv+1 ----
        #pragma unroll
        for (int nh = 0; nh < 2; ++nh) {
            int nt = wv * 2 + nh, pos = nt * 16 + tl;
            union { bf16x8 v; u32 d[4]; } BH[2], BL[2];
            #pragma unroll
            for (int k = 0; k < 2; ++k) {
                const u32* ph = &XTh[pos * 35 + k * 16 + g * 4];
                const u32* pl = &XTl[pos * 35 + k * 16 + g * 4];
                BH[k].d[0] = ph[0]; BH[k].d[1] = ph[1]; BH[k].d[2] = ph[2]; BH[k].d[3] = ph[3];
                BL[k].d[0] = pl[0]; BL[k].d[1] = pl[1]; BL[k].d[2] = pl[2]; BL[k].d[3] = pl[3];
            }
            float nz = NZ[pos];
            int t = pos & 31, hwl = pos >> 5, side = g >> 1, g1 = g & 1;
            int off = t * 40 + hwl * 8 + g1 * 4;
            #pragma unroll
            for (int mt = 0; mt < 4; ++mt) {
                f32x4 a = {0.f, 0.f, 0.f, 0.f};
                #pragma unroll
                for (int k = 0; k < 2; ++k) {
                    a = __builtin_amdgcn_mfma_f32_16x16x32_bf16(WH[mt][k], BH[k].v, a, 0, 0, 0);
                    a = __builtin_amdgcn_mfma_f32_16x16x32_bf16(WH[mt][k], BL[k].v, a, 0, 0, 0);
                    a = __builtin_amdgcn_mfma_f32_16x16x32_bf16(WL[mt][k], BH[k].v, a, 0, 0, 0);
                }
                u32 uu[4], lu[4];
                #pragma unroll
                for (int j = 0; j < 4; ++j) {
                    float yv = a[j] + (&np4[mt].x)[j] * nz + (&bp4[mt].x)[j];
                    u32 uy = __float_as_uint(yv);
                    float res = yv - __uint_as_float(uy & 0xFFFF0000u);
                    uu[j] = uy; lu[j] = __float_as_uint(res);
                }
                u16* dh = (side ? KTh[mt] : QTh[mt]) + off;
                u16* dl = (side ? KTl[mt] : QTl[mt]) + off;
                *(uint2*)dh = make_uint2((uu[0] >> 16) | (uu[1] & 0xFFFF0000u),
                                         (uu[2] >> 16) | (uu[3] & 0xFFFF0000u));
                *(uint2*)dl = make_uint2((lu[0] >> 16) | (lu[1] & 0xFFFF0000u),
                                         (lu[2] >> 16) | (lu[3] & 0xFFFF0000u));
            }
        }
        __syncthreads();
        // ---- score: wave tile (ti,tj) for all 4 heads; acc across subs ----
        int ar = (ti * 16 + tl) * 40 + g * 8;
        int br = (tj * 16 + tl) * 40 + g * 8;
        #pragma unroll
        for (int h = 0; h < 4; ++h) {
            bf16x8 Ah = *(const bf16x8*)&QTh[h][ar];
            bf16x8 Al = *(const bf16x8*)&QTl[h][ar];
            bf16x8 Bh = *(const bf16x8*)&KTh[h][br];
            bf16x8 Bl = *(const bf16x8*)&KTl[h][br];
            sacc[h] = __builtin_amdgcn_mfma_f32_16x16x32_bf16(Ah, Bh, sacc[h], 0, 0, 0);
            sacc[h] = __builtin_amdgcn_mfma_f32_16x16x32_bf16(Ah, Bl, sacc[h], 0, 0, 0);
            sacc[h] = __builtin_amdgcn_mfma_f32_16x16x32_bf16(Al, Bh, sacc[h], 0, 0, 0);
        }
    }
    float* Sbase = S + ((size_t)b * 8 + hg * 4) * 1024;
    #pragma unroll
    for (int h = 0; h < 4; ++h) {
        float* Sb = Sbase + h * 1024;
        #pragma unroll
        for (int jj = 0; jj < 4; ++jj)
            atomicAdd(&Sb[(ti * 16 + g * 4 + jj) * 32 + tj * 16 + tl], sacc[h][jj]);
    }
}

// ---------------- K4: softmax + MFMA v + MFMA PV + MFMA proj (hi/lo) -------
// grid 1024 = b x hwblk4; 256 thr (4 waves); LDS 74.75 KB -> 2 blocks/CU.
__global__ __launch_bounds__(256) void k_out(
        const float* __restrict__ x, const u16* __restrict__ wv_bf,
        const float* __restrict__ qnp, const float* __restrict__ qbp,
        const float* __restrict__ qnoise, const float* __restrict__ Sg,
        const u16* __restrict__ wp_bf, const float* __restrict__ pnp,
        const float* __restrict__ pbp, const float* __restrict__ pnoise,
        float* __restrict__ out) {
    int bidx = blockIdx.x;
    int b = bidx >> 8, hw0 = (bidx & 255) * 4;
    int tid = threadIdx.x;
    __shared__ u32   P32s[5120];   // 20 KB: [h][i(t)] bf16 pairs, row stride 20 u32
    __shared__ __align__(16) u16 V16[20480];  // 20 KB (bytes): [rv][t] bf16, 80B stride, XOR swz
    __shared__ __align__(16) float uni[8448]; // 33 KB: stage XT bf16 [pos][e]@70; ph2+: AT hi/lo bf16
    // ---- fused softmax -> P bf16 ----
    {
        int n = tid >> 5, i2 = tid & 31;
        const float* Srow = Sg + ((size_t)b * 8 + n) * 1024 + i2 * 32;
        float v[32];
        #pragma unroll
        for (int j4 = 0; j4 < 8; ++j4) {
            float4 s4 = *(const float4*)(Srow + j4 * 4);
            v[j4 * 4] = s4.x; v[j4 * 4 + 1] = s4.y;
            v[j4 * 4 + 2] = s4.z; v[j4 * 4 + 3] = s4.w;
        }
        float slope = exp2f(-(float)(n + 1));
        float m = -3e38f;
        #pragma unroll
        for (int j = 0; j < 32; ++j) {
            float val = v[j] * 0.011048543456039806f - slope * fabsf((float)(i2 - j));
            if (j <= i2) val = -1e18f;             // tril incl. diag masked
            v[j] = val; m = fmaxf(m, val);
        }
        float ssum = 0.f;
        #pragma unroll
        for (int j = 0; j < 32; ++j) { float e2 = expf(v[j] - m); v[j] = e2; ssum += e2; }
        float r = 1.f / ssum;
        #pragma unroll
        for (int jp = 0; jp < 16; ++jp)
            P32s[n * 640 + i2 * 20 + jp] = pack2(v[2 * jp] * r, v[2 * jp + 1] * r);
    }
    // ---- stage x -> XT bf16 [pos][e], row stride 70 u16 ----
    {
        u16* XTu = (u16*)uni;
        const float4* xb4 = (const float4*)(x + (size_t)b * CC * PP + (size_t)hw0 * 32);
        #pragma unroll
        for (int r4 = 0; r4 < 8; ++r4) {
            int idx = r4 * 256 + tid;             // 0..2047 float4s
            int e = idx >> 5, rem = idx & 31, posq = rem * 4;
            float4 xv = xb4[(size_t)e * (PP / 4) + rem];
            XTu[(posq + 0) * 70 + e] = f2b(xv.x);
            XTu[(posq + 1) * 70 + e] = f2b(xv.y);
            XTu[(posq + 2) * 70 + e] = f2b(xv.z);
            XTu[(posq + 3) * 70 + e] = f2b(xv.w);
        }
    }
    __syncthreads();
    int wv_ = tid >> 6, l = tid & 63, tl = l & 15, g = l >> 4;
    // ---- phase 1 (MFMA): V = Wv x + noise + bias -> V16 bf16 ----
    {
        const u32* XT32 = (const u32*)uni;
        const u16* wvb = wv_bf + (size_t)b * 4096;
        bf16x8 Af[4][2];
        #pragma unroll
        for (int mt = 0; mt < 4; ++mt)
            #pragma unroll
            for (int k = 0; k < 2; ++k)
                Af[mt][k] = *(const bf16x8*)(wvb + (mt * 16 + tl) * 64 + k * 32 + g * 8);
        #pragma unroll
        for (int nh = 0; nh < 2; ++nh) {
            int nt = 2 * wv_ + nh;
            f32x4 acc[4];
            #pragma unroll
            for (int mt = 0; mt < 4; ++mt) acc[mt] = (f32x4){0.f, 0.f, 0.f, 0.f};
            #pragma unroll
            for (int k = 0; k < 2; ++k) {
                int pos = nt * 16 + tl;
                union { bf16x8 v8; u32 d[4]; } B;
                const u32* xp = XT32 + pos * 35 + k * 16 + g * 4;
                B.d[0] = xp[0]; B.d[1] = xp[1]; B.d[2] = xp[2]; B.d[3] = xp[3];
                #pragma unroll
                for (int mt = 0; mt < 4; ++mt)
                    acc[mt] = __builtin_amdgcn_mfma_f32_16x16x32_bf16(Af[mt][k], B.v8, acc[mt], 0, 0, 0);
            }
            int t = (nt & 1) * 16 + tl;
            float nz = qnoise[(size_t)b * PP + (size_t)(hw0 + wv_) * 32 + t];
            #pragma unroll
            for (int mt = 0; mt < 4; ++mt) {
                float4 np4 = *(const float4*)(qnp + 128 + mt * 16 + g * 4);
                float4 bp4 = *(const float4*)(qbp + 128 + mt * 16 + g * 4);
                #pragma unroll
                for (int j = 0; j < 4; ++j) {
                    int ich = mt * 16 + g * 4 + j;
                    int rv = ich * 4 + wv_;
                    float y = acc[mt][j] + (&np4.x)[j] * nz + (&bp4.x)[j];
                    u32 bo = (u32)(rv * 80 + t * 2) ^ ((((u32)rv >> 4) & 3u) << 5);
                    *(u16*)((char*)V16 + bo) = f2b(y);
                }
            }
        }
    }
    __syncthreads();
    // ---- phase 2 (MFMA): A[r][t] = sum_j V[r][j] P[t][j] -> AT hi/lo bf16 ----
    // AT layout: [pos 128][i 64] u16, 128B rows, byte ^= ((pos&7)<<4); aliased in uni.
    u16* ATh = (u16*)uni;
    u16* ATl = ATh + 8192;
    {
        #pragma unroll
        for (int hh = 0; hh < 2; ++hh) {
            int h = 2 * wv_ + hh;
            bf16x8 Bp[2];
            #pragma unroll
            for (int n2 = 0; n2 < 2; ++n2) {
                const u32* pp = P32s + h * 640 + (n2 * 16 + tl) * 20 + g * 4;
                union { bf16x8 v8; u32 d[4]; } U;
                U.d[0] = pp[0]; U.d[1] = pp[1]; U.d[2] = pp[2]; U.d[3] = pp[3];
                Bp[n2] = U.v8;
            }
            #pragma unroll
            for (int mt2 = 0; mt2 < 2; ++mt2) {
                int rv = h * 32 + mt2 * 16 + tl;
                u32 bo = ((u32)(rv * 80) + (u32)g * 16) ^ ((((u32)rv >> 4) & 3u) << 5);
                bf16x8 Av = *(const bf16x8*)((const char*)V16 + bo);
                #pragma unroll
                for (int n2 = 0; n2 < 2; ++n2) {
                    f32x4 a4 = (f32x4){0.f, 0.f, 0.f, 0.f};
                    a4 = __builtin_amdgcn_mfma_f32_16x16x32_bf16(Av, Bp[n2], a4, 0, 0, 0);
                    int i = h * 8 + mt2 * 4 + g;
                    int t = n2 * 16 + tl;
                    #pragma unroll
                    for (int j = 0; j < 4; ++j) {
                        int row = j * 32 + t;            // pos = hwl*32 + t
                        u32 uy = __float_as_uint(a4[j]);
                        float res = a4[j] - __uint_as_float(uy & 0xFFFF0000u);
                        u32 ao = ((u32)(row * 128 + i * 2)) ^ (((u32)row & 7u) << 4);
                        *(u16*)((char*)ATh + ao) = (u16)(uy >> 16);
                        *(u16*)((char*)ATl + ao) = (u16)(__float_as_uint(res) >> 16);
                    }
                }
            }
        }
    }
    __syncthreads();
    // ---- phase 3 (MFMA): out[o][pos] = sum_i Wp[o][i] A[i][pos], hi/lo ----
    {
        bf16x8 WpH[4][2], WpL[4][2];
        #pragma unroll
        for (int mt = 0; mt < 4; ++mt)
            #pragma unroll
            for (int k = 0; k < 2; ++k) {
                const u16* wb = wp_bf + ((size_t)b * 64 + mt * 16 + tl) * 64 + k * 32 + g * 8;
                WpH[mt][k] = *(const bf16x8*)wb;
                WpL[mt][k] = *(const bf16x8*)(wb + 16384);
            }
        #pragma unroll
        for (int nh = 0; nh < 2; ++nh) {
            int pos = (wv_ * 2 + nh) * 16 + tl;
            union { bf16x8 v; u32 d[4]; } BH[2], BL[2];
            #pragma unroll
            for (int k = 0; k < 2; ++k) {
                u32 bo = ((u32)(pos * 128 + k * 64 + g * 16)) ^ (((u32)pos & 7u) << 4);
                BH[k].v = *(const bf16x8*)((const char*)ATh + bo);
                BL[k].v = *(const bf16x8*)((const char*)ATl + bo);
            }
            f32x4 dacc[4];
            #pragma unroll
            for (int mt = 0; mt < 4; ++mt) dacc[mt] = (f32x4){0.f, 0.f, 0.f, 0.f};
            #pragma unroll
            for (int k = 0; k < 2; ++k)
                #pragma unroll
                for (int mt = 0; mt < 4; ++mt) {
                    dacc[mt] = __builtin_amdgcn_mfma_f32_16x16x32_bf16(WpH[mt][k], BH[k].v, dacc[mt], 0, 0, 0);
                    dacc[mt] = __builtin_amdgcn_mfma_f32_16x16x32_bf16(WpH[mt][k], BL[k].v, dacc[mt], 0, 0, 0);
                    dacc[mt] = __builtin_amdgcn_mfma_f32_16x16x32_bf16(WpL[mt][k], BH[k].v, dacc[mt], 0, 0, 0);
                }
            int hwl = pos >> 5, t = pos & 31;
            float nz = pnoise[(size_t)b * PP + (size_t)(hw0 + hwl) * 32 + t];
            #pragma unroll
            for (int mt = 0; mt < 4; ++mt) {
                float4 npv = *(const float4*)(pnp + mt * 16 + g * 4);
                float4 bpv = *(const float4*)(pbp + mt * 16 + g * 4);
                #pragma unroll
                for (int jj = 0; jj < 4; ++jj) {
                    int o = mt * 16 + g * 4 + jj;
                    out[(size_t)(b * 64 + o) * PP + (size_t)(hw0 + hwl) * 32 + t]
                        = dacc[mt][jj] + (&npv.x)[jj] * nz + (&bpv.x)[jj];
                }
            }
        }
    }
}

// ---------------- sentinels ------------------------------------------------
__global__ __launch_bounds__(256) void k_zero(float* __restrict__ out, int n) {
    int i = blockIdx.x * 256 + threadIdx.x;
    if (i < n) out[i] = 0.f;
}
__global__ void k_code(float* __restrict__ out, float code) { out[0] = code; }

extern "C" void kernel_launch(void* const* d_in, const int* in_sizes, int n_in,
                              void* d_out, int out_size, void* d_ws, size_t ws_size,
                              hipStream_t stream) {
    float* out = (float*)d_out;
    const int exp_sizes[14] = {4*64*32768, 4*512, 192*64, 64*512, 64, 192, 192,
                               4*32768, 64*64, 64*512, 64, 64, 64, 4*32768};
    bool ok = (n_in == 14) && (out_size == 4*64*32768);
    if (ok) for (int k = 0; k < 14; ++k) ok = ok && (in_sizes[k] == exp_sizes[k]);
    if (!ok) {
        k_zero<<<(out_size + 255) / 256, 256, 0, stream>>>(out, out_size);
        k_code<<<1, 1, 0, stream>>>(out, 1000.f);
        return;
    }
    if (ws_size < 395264) {
        k_zero<<<(out_size + 255) / 256, 256, 0, stream>>>(out, out_size);
        k_code<<<1, 1, 0, stream>>>(out, 2000.f + (float)(ws_size >> 20));
        return;
    }
    char* ws = (char*)d_ws;
    float* S      = (float*)ws;               // 128 KB (4,8,32,32)
    u16*   wqk_bf = (u16*)  (ws + 131072);    // 128 KB (4, 256 rows hi+lo, 64e) bf16
    u16*   wv_bf  = (u16*)  (ws + 262144);    //  32 KB used (4,64ich,64e) bf16
    u16*   wp_bf  = (u16*)  (ws + 327680);    //  64 KB (hi: 4,64o,64i; lo at +16384 u16)
    float* s_sty  = (float*)(ws + 393216);    //   2 KB (4,128)

    k_style2 <<<512,  64,  0, stream>>>((const float*)d_in[1], (const float*)d_in[3],
                                        (const float*)d_in[4], (const float*)d_in[9],
                                        (const float*)d_in[10], s_sty);
    k_wnorm  <<<1024, 64,  0, stream>>>((const float*)d_in[2], (const float*)d_in[8],
                                        s_sty, wqk_bf, wv_bf, wp_bf, S);
    k_fscores<<<512,  256, 0, stream>>>((const float*)d_in[0], wqk_bf,
                                        (const float*)d_in[5], (const float*)d_in[6],
                                        (const float*)d_in[7], S);
    k_out    <<<1024, 256, 0, stream>>>((const float*)d_in[0], wv_bf,
                                        (const float*)d_in[5], (const float*)d_in[6],
                                        (const float*)d_in[7], S, wp_bf,
                                        (const float*)d_in[11], (const float*)d_in[12],
                                        (const float*)d_in[13], out);
    hipError_t e = hipGetLastError();
    if (e != hipSuccess) {
        k_zero<<<(out_size + 255) / 256, 256, 0, stream>>>(out, out_size);
        k_code<<<1, 1, 0, stream>>>(out, 3000.f + (float)e);
    }
}

// Round 4
// 154.535 us; speedup vs baseline: 1.3410x; 1.0689x over previous
//
#include <hip/hip_runtime.h>

typedef unsigned short u16;
typedef unsigned int   u32;
typedef __attribute__((ext_vector_type(8))) short bf16x8;   // 8 bf16 = 4 VGPRs
typedef __attribute__((ext_vector_type(4))) float f32x4;

#define PP 32768          // H*W*T
#define CC 64

__device__ __forceinline__ u16 f2b(float f) {
    u32 u; __builtin_memcpy(&u, &f, 4);
    u32 r = (u + 0x7FFFu + ((u >> 16) & 1u)) >> 16;
    return (u16)r;
}
__device__ __forceinline__ u32 pack2(float lo, float hi) {
    return (u32)f2b(lo) | ((u32)f2b(hi) << 16);
}

// ---------------- K1: style dot, one output channel per block --------------
__global__ __launch_bounds__(64) void k_style2(
        const float* __restrict__ style, const float* __restrict__ qkv_lw,
        const float* __restrict__ qkv_lb, const float* __restrict__ proj_lw,
        const float* __restrict__ proj_lb, float* __restrict__ s_out) {
    int id = blockIdx.x;
    int b = id >> 7, sel = (id >> 6) & 1, o = id & 63;
    int t = threadIdx.x;
    const float* lw = sel ? proj_lw : qkv_lw;
    const float* lb = sel ? proj_lb : qkv_lb;
    const float* st = style + b * 512 + t * 8;
    const float* wr = lw + (size_t)o * 512 + t * 8;
    float4 s0 = *(const float4*)st, s1 = *(const float4*)(st + 4);
    float4 w0 = *(const float4*)wr, w1 = *(const float4*)(wr + 4);
    float p = s0.x*w0.x + s0.y*w0.y + s0.z*w0.z + s0.w*w0.w
            + s1.x*w1.x + s1.y*w1.y + s1.z*w1.z + s1.w*w1.w;
    #pragma unroll
    for (int off = 32; off > 0; off >>= 1) p += __shfl_xor(p, off, 64);
    if (t == 0) s_out[b * 128 + sel * 64 + o] = p + lb[o];
}

// ---------------- K2: normalized modulated weights + S zero ----------------
// wqk_bf[b]: 256 rows x 64e u16: rows 0..127 = hi(q0-63,k0-63), rows 128..255 = lo.
// wv_bf[b][ich][e] bf16; wp_bf: hi [b][o][i] u16 + lo at +16384.
__global__ __launch_bounds__(64) void k_wnorm(
        const float* __restrict__ qkv_w, const float* __restrict__ proj_w,
        const float* __restrict__ s, u16* __restrict__ wqk_bf,
        u16* __restrict__ wv_bf, u16* __restrict__ wp_bf, float* __restrict__ S) {
    int id = blockIdx.x;           // 4 * 256
    int b = id >> 8, o = id & 255, i = threadIdx.x;
    if (i < 32) S[(size_t)id * 32 + i] = 0.f;     // 1024*32 = |S| exactly
    float wv;
    if (o < 192) wv = qkv_w[o * 64 + i] * s[b * 128 + i];
    else         wv = proj_w[(o - 192) * 64 + i] * s[b * 128 + 64 + i];
    float sq = wv * wv;
    #pragma unroll
    for (int off = 32; off > 0; off >>= 1) sq += __shfl_xor(sq, off, 64);
    float val = wv * rsqrtf(sq + 1e-8f);
    if (o < 128) {
        u32 uv = __float_as_uint(val);
        float res = val - __uint_as_float(uv & 0xFFFF0000u);
        wqk_bf[((size_t)b * 256 + o) * 64 + i]       = (u16)(uv >> 16);
        wqk_bf[((size_t)b * 256 + 128 + o) * 64 + i] = (u16)(__float_as_uint(res) >> 16);
    }
    else if (o < 192) wv_bf[((size_t)b * 64 + (o - 128)) * 64 + i] = f2b(val);
    else {
        int o2 = o - 192;
        u32 uv = __float_as_uint(val);
        float res = val - __uint_as_float(uv & 0xFFFF0000u);
        wp_bf[((size_t)b * 64 + o2) * 64 + i]         = (u16)(uv >> 16);
        wp_bf[16384 + ((size_t)b * 64 + o2) * 64 + i] = (u16)(__float_as_uint(res) >> 16);
    }
}

// ---------------- K3: MFMA q,k recompute + MFMA scores, 4 heads/block ------
// grid 512 = b(4) x hg(2) x chunk(64 of 16hw); 256 thr; LDS 77.6 KB -> 2 blk/CU.
// 4 sub-chunks of 128 pos; staging amortized over 4 heads.
__global__ __launch_bounds__(256) void k_fscores(
        const float* __restrict__ x, const u16* __restrict__ wqk_bf,
        const float* __restrict__ qnp, const float* __restrict__ qbp,
        const float* __restrict__ qnoise, float* __restrict__ S) {
    int bidx = blockIdx.x;
    int b = bidx >> 7, hg = (bidx >> 6) & 1, chunk = bidx & 63;
    int tid = threadIdx.x;
    __shared__ u32   XTh[4480];    // [pos 128][e2 35] hi pairs (u16 stride 70)
    __shared__ u32   XTl[4480];    // lo pairs
    __shared__ float NZ[128];
    __shared__ __align__(16) u16 QTh[4][1288], QTl[4][1288];  // [head][t*40 + r]
    __shared__ __align__(16) u16 KTh[4][1288], KTl[4][1288];

    int wv = tid >> 6, l = tid & 63, tl = l & 15, g = l >> 4;
    // A-frag weights for 4 heads: tl<8 -> q-ch, tl>=8 -> k-ch (row +64)
    bf16x8 WH[4][2], WL[4][2];
    #pragma unroll
    for (int mt = 0; mt < 4; ++mt) {
        int n = hg * 4 + mt;
        int wrow = n * 8 + (tl & 7) + (tl >> 3) * 64;
        const u16* wpb = wqk_bf + (size_t)b * 16384 + wrow * 64;
        #pragma unroll
        for (int k = 0; k < 2; ++k) {
            WH[mt][k] = *(const bf16x8*)(wpb + k * 32 + g * 8);
            WL[mt][k] = *(const bf16x8*)(wpb + 8192 + k * 32 + g * 8);
        }
    }
    // epilogue params per head: D rows r=g*4+j -> side=(g>>1), c=(g&1)*4+j
    float4 np4[4], bp4[4];
    #pragma unroll
    for (int mt = 0; mt < 4; ++mt) {
        int pidx = (g >> 1) * 64 + (hg * 4 + mt) * 8 + (g & 1) * 4;
        np4[mt] = *(const float4*)(qnp + pidx);
        bp4[mt] = *(const float4*)(qbp + pidx);
    }
    int ti = wv >> 1, tj = wv & 1;
    f32x4 sacc[4];
    #pragma unroll
    for (int h = 0; h < 4; ++h) sacc[h] = (f32x4){0.f, 0.f, 0.f, 0.f};

    #pragma unroll 1
    for (int sub = 0; sub < 4; ++sub) {
        // ---- stage x sub-chunk (128 pos x 64 e) as hi/lo bf16, e-paired ----
        const float* xc = x + (size_t)b * CC * PP + chunk * 512 + sub * 128;
        #pragma unroll
        for (int r2 = 0; r2 < 4; ++r2) {
            int idx = r2 * 256 + tid;            // 0..1023
            int e2 = idx >> 5, rem = idx & 31;   // e-pair, float4-within-row
            const float* pa = xc + (size_t)(2 * e2) * PP + rem * 4;
            float4 fa = *(const float4*)pa;
            float4 fb = *(const float4*)(pa + PP);
            #pragma unroll
            for (int j = 0; j < 4; ++j) {
                float va = (&fa.x)[j], vb = (&fb.x)[j];
                u32 ua = __float_as_uint(va), ub = __float_as_uint(vb);
                float ra = va - __uint_as_float(ua & 0xFFFF0000u);
                float rb = vb - __uint_as_float(ub & 0xFFFF0000u);
                int p = (rem * 4 + j) * 35 + e2;
                XTh[p] = (ua >> 16) | (ub & 0xFFFF0000u);
                XTl[p] = (__float_as_uint(ra) >> 16) | (__float_as_uint(rb) & 0xFFFF0000u);
            }
        }
        if (tid < 32)
            *(float4*)&NZ[tid * 4] = *(const float4*)
                (qnoise + (size_t)b * PP + chunk * 512 + sub * 128 + tid * 4);
        __syncthreads();
        // ---- phase 1: q||k for 4 heads; wave owns ntiles 2wv,2wv+1 ----
        #pragma unroll
        for (int nh = 0; nh < 2; ++nh) {
            int nt = wv * 2 + nh, pos = nt * 16 + tl;
            union { bf16x8 v; u32 d[4]; } BH[2], BL[2];
            #pragma unroll
            for (int k = 0; k < 2; ++k) {
                const u32* ph = &XTh[pos * 35 + k * 16 + g * 4];
                const u32* pl = &XTl[pos * 35 + k * 16 + g * 4];
                BH[k].d[0] = ph[0]; BH[k].d[1] = ph[1]; BH[k].d[2] = ph[2]; BH[k].d[3] = ph[3];
                BL[k].d[0] = pl[0]; BL[k].d[1] = pl[1]; BL[k].d[2] = pl[2]; BL[k].d[3] = pl[3];
            }
            float nz = NZ[pos];
            int t = pos & 31, hwl = pos >> 5, side = g >> 1, g1 = g & 1;
            int off = t * 40 + hwl * 8 + g1 * 4;
            #pragma unroll
            for (int mt = 0; mt < 4; ++mt) {
                f32x4 a = {0.f, 0.f, 0.f, 0.f};
                #pragma unroll
                for (int k = 0; k < 2; ++k) {
                    a = __builtin_amdgcn_mfma_f32_16x16x32_bf16(WH[mt][k], BH[k].v, a, 0, 0, 0);
                    a = __builtin_amdgcn_mfma_f32_16x16x32_bf16(WH[mt][k], BL[k].v, a, 0, 0, 0);
                    a = __builtin_amdgcn_mfma_f32_16x16x32_bf16(WL[mt][k], BH[k].v, a, 0, 0, 0);
                }
                u32 uu[4], lu[4];
                #pragma unroll
                for (int j = 0; j < 4; ++j) {
                    float yv = a[j] + (&np4[mt].x)[j] * nz + (&bp4[mt].x)[j];
                    u32 uy = __float_as_uint(yv);
                    float res = yv - __uint_as_float(uy & 0xFFFF0000u);
                    uu[j] = uy; lu[j] = __float_as_uint(res);
                }
                u16* dh = (side ? KTh[mt] : QTh[mt]) + off;
                u16* dl = (side ? KTl[mt] : QTl[mt]) + off;
                *(uint2*)dh = make_uint2((uu[0] >> 16) | (uu[1] & 0xFFFF0000u),
                                         (uu[2] >> 16) | (uu[3] & 0xFFFF0000u));
                *(uint2*)dl = make_uint2((lu[0] >> 16) | (lu[1] & 0xFFFF0000u),
                                         (lu[2] >> 16) | (lu[3] & 0xFFFF0000u));
            }
        }
        __syncthreads();
        // ---- score: wave tile (ti,tj) for all 4 heads; acc across subs ----
        int ar = (ti * 16 + tl) * 40 + g * 8;
        int br = (tj * 16 + tl) * 40 + g * 8;
        #pragma unroll
        for (int h = 0; h < 4; ++h) {
            bf16x8 Ah = *(const bf16x8*)&QTh[h][ar];
            bf16x8 Al = *(const bf16x8*)&QTl[h][ar];
            bf16x8 Bh = *(const bf16x8*)&KTh[h][br];
            bf16x8 Bl = *(const bf16x8*)&KTl[h][br];
            sacc[h] = __builtin_amdgcn_mfma_f32_16x16x32_bf16(Ah, Bh, sacc[h], 0, 0, 0);
            sacc[h] = __builtin_amdgcn_mfma_f32_16x16x32_bf16(Ah, Bl, sacc[h], 0, 0, 0);
            sacc[h] = __builtin_amdgcn_mfma_f32_16x16x32_bf16(Al, Bh, sacc[h], 0, 0, 0);
        }
    }
    float* Sbase = S + ((size_t)b * 8 + hg * 4) * 1024;
    #pragma unroll
    for (int h = 0; h < 4; ++h) {
        float* Sb = Sbase + h * 1024;
        #pragma unroll
        for (int jj = 0; jj < 4; ++jj)
            atomicAdd(&Sb[(ti * 16 + g * 4 + jj) * 32 + tj * 16 + tl], sacc[h][jj]);
    }
}

// ---------------- K4: softmax + MFMA v + MFMA PV + MFMA proj (hi/lo) -------
// grid 1024 = b x hwblk4; 256 thr (4 waves); LDS 74752 B -> 2 blocks/CU.
// (r3 bug: V16 was declared 20480 u16 = 40 KB, 1 blk/CU; intent is 20480 BYTES.)
__global__ __launch_bounds__(256) void k_out(
        const float* __restrict__ x, const u16* __restrict__ wv_bf,
        const float* __restrict__ qnp, const float* __restrict__ qbp,
        const float* __restrict__ qnoise, const float* __restrict__ Sg,
        const u16* __restrict__ wp_bf, const float* __restrict__ pnp,
        const float* __restrict__ pbp, const float* __restrict__ pnoise,
        float* __restrict__ out) {
    int bidx = blockIdx.x;
    int b = bidx >> 8, hw0 = (bidx & 255) * 4;
    int tid = threadIdx.x;
    __shared__ u32   P32s[5120];   // 20 KB: [h][i(t)] bf16 pairs, row stride 20 u32
    __shared__ __align__(16) u16 V16[10240];  // 20 KB: [rv][t] bf16, 80B stride, XOR swz
    __shared__ __align__(16) float uni[8448]; // 33 KB: stage XT bf16 pairs [pos][e2]@35u32; ph2+: AT hi/lo bf16
    // ---- fused softmax -> P bf16 ----
    {
        int n = tid >> 5, i2 = tid & 31;
        const float* Srow = Sg + ((size_t)b * 8 + n) * 1024 + i2 * 32;
        float v[32];
        #pragma unroll
        for (int j4 = 0; j4 < 8; ++j4) {
            float4 s4 = *(const float4*)(Srow + j4 * 4);
            v[j4 * 4] = s4.x; v[j4 * 4 + 1] = s4.y;
            v[j4 * 4 + 2] = s4.z; v[j4 * 4 + 3] = s4.w;
        }
        float slope = exp2f(-(float)(n + 1));
        float m = -3e38f;
        #pragma unroll
        for (int j = 0; j < 32; ++j) {
            float val = v[j] * 0.011048543456039806f - slope * fabsf((float)(i2 - j));
            if (j <= i2) val = -1e18f;             // tril incl. diag masked
            v[j] = val; m = fmaxf(m, val);
        }
        float ssum = 0.f;
        #pragma unroll
        for (int j = 0; j < 32; ++j) { float e2 = expf(v[j] - m); v[j] = e2; ssum += e2; }
        float r = 1.f / ssum;
        #pragma unroll
        for (int jp = 0; jp < 16; ++jp)
            P32s[n * 640 + i2 * 20 + jp] = pack2(v[2 * jp] * r, v[2 * jp + 1] * r);
    }
    // ---- stage x -> XT bf16 e-pairs [pos][e2], row stride 35 u32 ----
    {
        u32* XTu = (u32*)uni;
        const float* xc = x + (size_t)b * CC * PP + (size_t)hw0 * 32;
        #pragma unroll
        for (int r2 = 0; r2 < 4; ++r2) {
            int idx = r2 * 256 + tid;            // 0..1023
            int e2 = idx >> 5, rem = idx & 31;   // e-pair, float4-within-row
            const float* pa = xc + (size_t)(2 * e2) * PP + rem * 4;
            float4 fa = *(const float4*)pa;
            float4 fb = *(const float4*)(pa + PP);
            #pragma unroll
            for (int j = 0; j < 4; ++j) {
                u32 ua = __float_as_uint((&fa.x)[j]), ub = __float_as_uint((&fb.x)[j]);
                // round-to-nearest-even bf16 (match f2b)
                u32 ha = (ua + 0x7FFFu + ((ua >> 16) & 1u)) & 0xFFFF0000u;
                u32 hb = (ub + 0x7FFFu + ((ub >> 16) & 1u)) & 0xFFFF0000u;
                XTu[(rem * 4 + j) * 35 + e2] = (ha >> 16) | hb;
            }
        }
    }
    __syncthreads();
    int wv_ = tid >> 6, l = tid & 63, tl = l & 15, g = l >> 4;
    // ---- phase 1 (MFMA): V = Wv x + noise + bias -> V16 bf16 ----
    {
        const u32* XT32 = (const u32*)uni;
        const u16* wvb = wv_bf + (size_t)b * 4096;
        bf16x8 Af[4][2];
        #pragma unroll
        for (int mt = 0; mt < 4; ++mt)
            #pragma unroll
            for (int k = 0; k < 2; ++k)
                Af[mt][k] = *(const bf16x8*)(wvb + (mt * 16 + tl) * 64 + k * 32 + g * 8);
        #pragma unroll
        for (int nh = 0; nh < 2; ++nh) {
            int nt = 2 * wv_ + nh;
            f32x4 acc[4];
            #pragma unroll
            for (int mt = 0; mt < 4; ++mt) acc[mt] = (f32x4){0.f, 0.f, 0.f, 0.f};
            #pragma unroll
            for (int k = 0; k < 2; ++k) {
                int pos = nt * 16 + tl;
                union { bf16x8 v8; u32 d[4]; } B;
                const u32* xp = XT32 + pos * 35 + k * 16 + g * 4;
                B.d[0] = xp[0]; B.d[1] = xp[1]; B.d[2] = xp[2]; B.d[3] = xp[3];
                #pragma unroll
                for (int mt = 0; mt < 4; ++mt)
                    acc[mt] = __builtin_amdgcn_mfma_f32_16x16x32_bf16(Af[mt][k], B.v8, acc[mt], 0, 0, 0);
            }
            int t = (nt & 1) * 16 + tl;
            float nz = qnoise[(size_t)b * PP + (size_t)(hw0 + wv_) * 32 + t];
            #pragma unroll
            for (int mt = 0; mt < 4; ++mt) {
                float4 np4 = *(const float4*)(qnp + 128 + mt * 16 + g * 4);
                float4 bp4 = *(const float4*)(qbp + 128 + mt * 16 + g * 4);
                #pragma unroll
                for (int j = 0; j < 4; ++j) {
                    int ich = mt * 16 + g * 4 + j;
                    int rv = ich * 4 + wv_;
                    float y = acc[mt][j] + (&np4.x)[j] * nz + (&bp4.x)[j];
                    u32 bo = (u32)(rv * 80 + t * 2) ^ ((((u32)rv >> 4) & 3u) << 5);
                    *(u16*)((char*)V16 + bo) = f2b(y);
                }
            }
        }
    }
    __syncthreads();
    // ---- phase 2 (MFMA): A[r][t] = sum_j V[r][j] P[t][j] -> AT hi/lo bf16 ----
    // AT layout: [pos 128][i 64] u16, 128B rows, byte ^= ((pos&7)<<4); aliased in uni.
    u16* ATh = (u16*)uni;
    u16* ATl = ATh + 8192;
    {
        #pragma unroll
        for (int hh = 0; hh < 2; ++hh) {
            int h = 2 * wv_ + hh;
            bf16x8 Bp[2];
            #pragma unroll
            for (int n2 = 0; n2 < 2; ++n2) {
                const u32* pp = P32s + h * 640 + (n2 * 16 + tl) * 20 + g * 4;
                union { bf16x8 v8; u32 d[4]; } U;
                U.d[0] = pp[0]; U.d[1] = pp[1]; U.d[2] = pp[2]; U.d[3] = pp[3];
                Bp[n2] = U.v8;
            }
            #pragma unroll
            for (int mt2 = 0; mt2 < 2; ++mt2) {
                int rv = h * 32 + mt2 * 16 + tl;
                u32 bo = ((u32)(rv * 80) + (u32)g * 16) ^ ((((u32)rv >> 4) & 3u) << 5);
                bf16x8 Av = *(const bf16x8*)((const char*)V16 + bo);
                #pragma unroll
                for (int n2 = 0; n2 < 2; ++n2) {
                    f32x4 a4 = (f32x4){0.f, 0.f, 0.f, 0.f};
                    a4 = __builtin_amdgcn_mfma_f32_16x16x32_bf16(Av, Bp[n2], a4, 0, 0, 0);
                    int i = h * 8 + mt2 * 4 + g;
                    int t = n2 * 16 + tl;
                    #pragma unroll
                    for (int j = 0; j < 4; ++j) {
                        int row = j * 32 + t;            // pos = hwl*32 + t
                        u32 uy = __float_as_uint(a4[j]);
                        float res = a4[j] - __uint_as_float(uy & 0xFFFF0000u);
                        u32 ao = ((u32)(row * 128 + i * 2)) ^ (((u32)row & 7u) << 4);
                        *(u16*)((char*)ATh + ao) = (u16)(uy >> 16);
                        *(u16*)((char*)ATl + ao) = (u16)(__float_as_uint(res) >> 16);
                    }
                }
            }
        }
    }
    __syncthreads();
    // ---- phase 3 (MFMA): out[o][pos] = sum_i Wp[o][i] A[i][pos], hi/lo ----
    {
        bf16x8 WpH[4][2], WpL[4][2];
        #pragma unroll
        for (int mt = 0; mt < 4; ++mt)
            #pragma unroll
            for (int k = 0; k < 2; ++k) {
                const u16* wb = wp_bf + ((size_t)b * 64 + mt * 16 + tl) * 64 + k * 32 + g * 8;
                WpH[mt][k] = *(const bf16x8*)wb;
                WpL[mt][k] = *(const bf16x8*)(wb + 16384);
            }
        #pragma unroll
        for (int nh = 0; nh < 2; ++nh) {
            int pos = (wv_ * 2 + nh) * 16 + tl;
            union { bf16x8 v; u32 d[4]; } BH[2], BL[2];
            #pragma unroll
            for (int k = 0; k < 2; ++k) {
                u32 bo = ((u32)(pos * 128 + k * 64 + g * 16)) ^ (((u32)pos & 7u) << 4);
                BH[k].v = *(const bf16x8*)((const char*)ATh + bo);
                BL[k].v = *(const bf16x8*)((const char*)ATl + bo);
            }
            f32x4 dacc[4];
            #pragma unroll
            for (int mt = 0; mt < 4; ++mt) dacc[mt] = (f32x4){0.f, 0.f, 0.f, 0.f};
            #pragma unroll
            for (int k = 0; k < 2; ++k)
                #pragma unroll
                for (int mt = 0; mt < 4; ++mt) {
                    dacc[mt] = __builtin_amdgcn_mfma_f32_16x16x32_bf16(WpH[mt][k], BH[k].v, dacc[mt], 0, 0, 0);
                    dacc[mt] = __builtin_amdgcn_mfma_f32_16x16x32_bf16(WpH[mt][k], BL[k].v, dacc[mt], 0, 0, 0);
                    dacc[mt] = __builtin_amdgcn_mfma_f32_16x16x32_bf16(WpL[mt][k], BH[k].v, dacc[mt], 0, 0, 0);
                }
            int hwl = pos >> 5, t = pos & 31;
            float nz = pnoise[(size_t)b * PP + (size_t)(hw0 + hwl) * 32 + t];
            #pragma unroll
            for (int mt = 0; mt < 4; ++mt) {
                float4 npv = *(const float4*)(pnp + mt * 16 + g * 4);
                float4 bpv = *(const float4*)(pbp + mt * 16 + g * 4);
                #pragma unroll
                for (int jj = 0; jj < 4; ++jj) {
                    int o = mt * 16 + g * 4 + jj;
                    out[(size_t)(b * 64 + o) * PP + (size_t)(hw0 + hwl) * 32 + t]
                        = dacc[mt][jj] + (&npv.x)[jj] * nz + (&bpv.x)[jj];
                }
            }
        }
    }
}

// ---------------- sentinels ------------------------------------------------
__global__ __launch_bounds__(256) void k_zero(float* __restrict__ out, int n) {
    int i = blockIdx.x * 256 + threadIdx.x;
    if (i < n) out[i] = 0.f;
}
__global__ void k_code(float* __restrict__ out, float code) { out[0] = code; }

extern "C" void kernel_launch(void* const* d_in, const int* in_sizes, int n_in,
                              void* d_out, int out_size, void* d_ws, size_t ws_size,
                              hipStream_t stream) {
    float* out = (float*)d_out;
    const int exp_sizes[14] = {4*64*32768, 4*512, 192*64, 64*512, 64, 192, 192,
                               4*32768, 64*64, 64*512, 64, 64, 64, 4*32768};
    bool ok = (n_in == 14) && (out_size == 4*64*32768);
    if (ok) for (int k = 0; k < 14; ++k) ok = ok && (in_sizes[k] == exp_sizes[k]);
    if (!ok) {
        k_zero<<<(out_size + 255) / 256, 256, 0, stream>>>(out, out_size);
        k_code<<<1, 1, 0, stream>>>(out, 1000.f);
        return;
    }
    if (ws_size < 395264) {
        k_zero<<<(out_size + 255) / 256, 256, 0, stream>>>(out, out_size);
        k_code<<<1, 1, 0, stream>>>(out, 2000.f + (float)(ws_size >> 20));
        return;
    }
    char* ws = (char*)d_ws;
    float* S      = (float*)ws;               // 128 KB (4,8,32,32)
    u16*   wqk_bf = (u16*)  (ws + 131072);    // 128 KB (4, 256 rows hi+lo, 64e) bf16
    u16*   wv_bf  = (u16*)  (ws + 262144);    //  32 KB used (4,64ich,64e) bf16
    u16*   wp_bf  = (u16*)  (ws + 327680);    //  64 KB (hi: 4,64o,64i; lo at +16384 u16)
    float* s_sty  = (float*)(ws + 393216);    //   2 KB (4,128)

    k_style2 <<<512,  64,  0, stream>>>((const float*)d_in[1], (const float*)d_in[3],
                                        (const float*)d_in[4], (const float*)d_in[9],
                                        (const float*)d_in[10], s_sty);
    k_wnorm  <<<1024, 64,  0, stream>>>((const float*)d_in[2], (const float*)d_in[8],
                                        s_sty, wqk_bf, wv_bf, wp_bf, S);
    k_fscores<<<512,  256, 0, stream>>>((const float*)d_in[0], wqk_bf,
                                        (const float*)d_in[5], (const float*)d_in[6],
                                        (const float*)d_in[7], S);
    k_out    <<<1024, 256, 0, stream>>>((const float*)d_in[0], wv_bf,
                                        (const float*)d_in[5], (const float*)d_in[6],
                                        (const float*)d_in[7], S, wp_bf,
                                        (const float*)d_in[11], (const float*)d_in[12],
                                        (const float*)d_in[13], out);
    hipError_t e = hipGetLastError();
    if (e != hipSuccess) {
        k_zero<<<(out_size + 255) / 256, 256, 0, stream>>>(out, out_size);
        k_code<<<1, 1, 0, stream>>>(out, 3000.f + (float)e);
    }
}